// Round 8
// baseline (421.208 us; speedup 1.0000x reference)
//
#include <hip/hip_runtime.h>
#include <stdint.h>
#include <math.h>

// Problem constants (B=4,S=2048 -> T=8192; H=1024; 2H=2048; E=8; K=2)
#define T_TOK 8192
#define H_DIM 1024
#define H2    2048
#define NE    8

typedef unsigned short u16;
typedef __attribute__((ext_vector_type(8))) short bf16x8;   // 8 bf16 in 4 VGPRs
typedef __attribute__((ext_vector_type(4))) float f32x4;    // MFMA 16x16 C/D

__device__ __forceinline__ u16 f32_to_bf16(float f) {
  union { float f; unsigned u; } c; c.f = f;
  unsigned u = c.u + 0x7fffu + ((c.u >> 16) & 1u);  // RNE
  return (u16)(u >> 16);
}
__device__ __forceinline__ float bf2f(u16 v) {
  union { unsigned u; float f; } c; c.u = (unsigned)v << 16; return c.f;
}

// fast gelu (tanh form), |err| vs exact erf-gelu <= ~1e-3 (absmax 1.56e-2
// vs threshold 4.9e-2, stable across rounds)
__device__ __forceinline__ float fast_gelu(float v) {
  float u = v * v;
  float z2 = v * fmaf(u, 0.1029437f, 2.3022078f);
  float e = __builtin_amdgcn_exp2f(z2);
  float r = __builtin_amdgcn_rcpf(1.0f + e);
  return v - v * r;
}

// async global->LDS, 16B per lane. LDS dest is wave-uniform base + lane*16;
// global address is per-lane (exploited for the XOR bank swizzle).
__device__ __forceinline__ void g2l16(const void* g, void* l) {
  __builtin_amdgcn_global_load_lds(
      (const __attribute__((address_space(1))) unsigned*)g,
      (__attribute__((address_space(3))) unsigned*)l, 16, 0, 0);
}

// exclusive prefix of 8 counts, computed per-block
__device__ __forceinline__ int prefix_base(const int* counts, int e) {
  int b = 0;
#pragma unroll
  for (int j = 0; j < NE; j++) b += (j < e) ? counts[j] : 0;
  return b;
}

// ---------------- Prep: router + zero counts + zero out (out is now
// accumulated atomically by g2, so it must start at 0 EVERY graph replay --
// prep re-zeroes each launch). w1 cvt moved to build's grid.
__global__ __launch_bounds__(256) void prep_kernel(
    const float* __restrict__ x, const float* __restrict__ rw,
    u16* __restrict__ xb, int* __restrict__ tope, float2* __restrict__ gate2,
    int* __restrict__ counts, float* __restrict__ out_zero) {
  int blk = blockIdx.x;
  if (blk == 0 && threadIdx.x < NE) counts[threadIdx.x] = 0;

  // ---- zero out: 2048 blocks x 1024 f4 = 32 MB exactly (rides router BW)
  {
    float4 z = make_float4(0.f, 0.f, 0.f, 0.f);
    float4* o4 = (float4*)out_zero;
    int b0 = blk * 1024 + threadIdx.x;
#pragma unroll
    for (int k = 0; k < 4; ++k) o4[b0 + k * 256] = z;
  }

  // ---- router: one wave per token, fp64 logits (exact ranking vs ref)
  int wave = threadIdx.x >> 6;
  int lane = threadIdx.x & 63;
  int t = blk * 4 + wave;
  const float4* x4 = (const float4*)(x + (size_t)t * H_DIM);
  const float4* rw4 = (const float4*)rw;
  u16* xbrow = xb + (size_t)t * H_DIM;

  double acc[NE];
#pragma unroll
  for (int e = 0; e < NE; e++) acc[e] = 0.0;
#pragma unroll
  for (int i = 0; i < 4; i++) {
    int c = lane + 64 * i;
    float4 xv = x4[c];
    ushort4 bv = make_ushort4(f32_to_bf16(xv.x), f32_to_bf16(xv.y),
                              f32_to_bf16(xv.z), f32_to_bf16(xv.w));
    *(ushort4*)(xbrow + c * 4) = bv;
#pragma unroll
    for (int e = 0; e < NE; e++) {
      float4 wv = rw4[e * 256 + c];
      acc[e] += (double)xv.x * wv.x + (double)xv.y * wv.y +
                (double)xv.z * wv.z + (double)xv.w * wv.w;
    }
  }
#pragma unroll
  for (int off = 32; off >= 1; off >>= 1)
#pragma unroll
    for (int e = 0; e < NE; e++) acc[e] += __shfl_xor(acc[e], off, 64);

  if (lane == 0) {
    int e0 = 0; double v0 = acc[0];
#pragma unroll
    for (int e = 1; e < NE; e++) if (acc[e] > v0) { v0 = acc[e]; e0 = e; }
    int e1 = -1; double v1 = -1e300;
#pragma unroll
    for (int e = 0; e < NE; e++) if (e != e0 && acc[e] > v1) { v1 = acc[e]; e1 = e; }
    double ex = exp(v1 - v0);
    tope[t] = e0 | (e1 << 8);
    gate2[t] = make_float2((float)(1.0 / (1.0 + ex)), (float)(ex / (1.0 + ex)));
  }
}

// ---------------- Build: blocks 0..31 = counting sort over 8 bins;
// blocks 32..2079 convert w1 f32->bf16 (2048 blocks x 2048 f4 = exact
// coverage) at full parallel BW (~18us) instead of serializing in prep.
__global__ __launch_bounds__(256) void build_kernel(
    const int* __restrict__ tope, int* __restrict__ counts,
    int* __restrict__ tok_list,
    const float* __restrict__ w1, u16* __restrict__ w1b) {
  if (blockIdx.x >= 32) {
    const float4* s4 = (const float4*)w1;
    int b0 = (blockIdx.x - 32) * 2048 + threadIdx.x;
#pragma unroll
    for (int k = 0; k < 8; ++k) {
      int i = b0 + k * 256;
      float4 v = s4[i];
      *(ushort4*)(w1b + (size_t)i * 4) = make_ushort4(
          f32_to_bf16(v.x), f32_to_bf16(v.y), f32_to_bf16(v.z), f32_to_bf16(v.w));
    }
    return;
  }
  __shared__ int cts[4][NE];
  __shared__ int gbase[NE];
  int tid = threadIdx.x, lane = tid & 63, w = tid >> 6;
  int t = blockIdx.x * 256 + tid;
  int pk = tope[t];
  int e0 = pk & 0xff, e1 = (pk >> 8) & 0xff;
  unsigned long long lt = ((unsigned long long)1 << lane) - 1;

  int r0 = 0, r1 = 0;
#pragma unroll
  for (int e = 0; e < NE; e++) {
    unsigned long long b0 = __ballot(e0 == e);
    unsigned long long b1 = __ballot(e1 == e);
    int n0 = __popcll(b0), n1 = __popcll(b1);
    if (e0 == e) r0 = __popcll(b0 & lt);
    if (e1 == e) r1 = n0 + __popcll(b1 & lt);
    if (lane == 0) cts[w][e] = n0 + n1;
  }
  __syncthreads();
  if (tid < NE) {
    int bt = cts[0][tid] + cts[1][tid] + cts[2][tid] + cts[3][tid];
    gbase[tid] = atomicAdd(&counts[tid], bt);
  }
  __syncthreads();
  int off0 = gbase[e0] + r0;
  int off1 = gbase[e1] + r1;
#pragma unroll
  for (int wp = 0; wp < 4; wp++) {
    if (wp < w) { off0 += cts[wp][e0]; off1 += cts[wp][e1]; }
  }
  tok_list[e0 * T_TOK + off0] = t;
  tok_list[e1 * T_TOK + off1] = t;
}

// ---------------- Grouped GEMM: R3's proven minimum-sync double-buffer
// schedule (256x256 tile, BK=64, 8 waves 2Mx4N, LDS 128 KiB, 0 bank
// conflicts, ~101us each).
// CVTW2: w2 cvt slices assigned ONLY to mt>=16 blocks (m0>=4096>=cnt in
//   any non-degenerate routing -> guaranteed-idle blocks; correct either
//   way). 1024 blocks x 4096 f4 = exact coverage, off the critical path.
// FUSEOUT: epilogue applies the gate and atomicAdds f32 into out directly
//   (token = tok_list[e][row]); eliminates the y buffer and the combine
//   kernel. Exactly 2 contributors per address, 64B-coalesced per quad.
//
// Per K-tile t (buf d = t&1): vmcnt(0); s_barrier; 24 ds_read_b128;
// stage(t+1) (8 g2l16, WAR-safe); setprio(1); 64 MFMA; setprio(0).
// XOR swizzle: phys 16B-chunk = logical ^ (row&7), pre-swizzled global
// source + linear LDS dest. XCD pinning: e = blockIdx&7 (grid %8==0).
template <int NKT, int NT, int OUTN, bool GATHER, bool GELU, bool CVTW2,
          bool FUSEOUT>
__global__ __launch_bounds__(512, 1) void moe_gemm(
    const u16* __restrict__ A, const u16* __restrict__ W,
    u16* __restrict__ O, const int* __restrict__ tok_list,
    const int* __restrict__ counts,
    const float* __restrict__ cvt_src, u16* __restrict__ cvt_dst,
    const int* __restrict__ tope, const float2* __restrict__ gate2,
    float* __restrict__ fout) {
  int e = blockIdx.x & 7;
  int rem = blockIdx.x >> 3;               // 0 .. 32*NT-1
  int mt = rem / NT, nt = rem % NT;
  if (CVTW2 && mt >= 16) {
    // w2 cvt slice on guaranteed-idle blocks: 8 f4/thread, coalesced
    int cid = e * (16 * NT) + (mt - 16) * NT + nt;   // 0..1023
    const float4* s4 = (const float4*)cvt_src;
    int b0 = cid * 4096 + threadIdx.x;
#pragma unroll
    for (int k = 0; k < 8; ++k) {
      int i = b0 + k * 512;
      float4 v = s4[i];
      *(ushort4*)(cvt_dst + (size_t)i * 4) = make_ushort4(
          f32_to_bf16(v.x), f32_to_bf16(v.y), f32_to_bf16(v.z), f32_to_bf16(v.w));
    }
  }
  int cnt = counts[e];
  int m0 = mt * 256;
  if (m0 >= cnt) return;
  int base = prefix_base(counts, e);
  const int K = NKT * 64;

  __shared__ u16 lA[2][16384];   // [dbuf][256][64] bf16 = 64 KB
  __shared__ u16 lB[2][16384];   // 64 KB

  int tid = threadIdx.x;
  int ln = tid & 63, w = tid >> 6;
  int wr = w >> 2, wc = w & 3;             // 2M x 4N wave grid
  int quad = ln >> 4, l16 = ln & 15;

  // ---- staging: call c covers rows c*64..c*64+63; 16B unit u = c*512+tid;
  // phys slot u&7 holds global chunk (u&7)^(row&7).
  const u16* We = W + (size_t)e * OUTN * K;
  const u16* aptr[4]; const u16* bptr[4];
#pragma unroll
  for (int c = 0; c < 4; ++c) {
    int u = c * 512 + tid;
    int row = u >> 3;
    int chunk = (u & 7) ^ (row & 7);
    int ar = m0 + row; if (ar > cnt - 1) ar = cnt - 1;
    const u16* ab;
    if (GATHER) ab = A + (size_t)tok_list[e * T_TOK + ar] * K;
    else        ab = A + (size_t)(base + ar) * K;
    aptr[c] = ab + chunk * 8;
    bptr[c] = We + (size_t)(nt * 256 + row) * K + chunk * 8;
  }

  // ---- read addresses (u16 within one 16384-u16 buffer)
  int adA[8][2], adB[4][2];
#pragma unroll
  for (int f = 0; f < 8; ++f) {
    int r = wr * 128 + f * 16 + l16;
#pragma unroll
    for (int kk = 0; kk < 2; ++kk)
      adA[f][kk] = r * 64 + ((((kk << 2) | quad) ^ (r & 7)) << 3);
  }
#pragma unroll
  for (int j = 0; j < 4; ++j) {
    int r = wc * 64 + j * 16 + l16;
#pragma unroll
    for (int kk = 0; kk < 2; ++kk)
      adB[j][kk] = r * 64 + ((((kk << 2) | quad) ^ (r & 7)) << 3);
  }

  f32x4 acc[8][4];
#pragma unroll
  for (int i = 0; i < 8; i++)
#pragma unroll
    for (int j = 0; j < 4; j++)
#pragma unroll
      for (int r = 0; r < 4; r++) acc[i][j][r] = 0.f;

  // prologue: tile 0 in flight
#pragma unroll
  for (int c = 0; c < 4; ++c) {
    g2l16(aptr[c], &lA[0][(c * 512 + tid) * 8]);
    g2l16(bptr[c], &lB[0][(c * 512 + tid) * 8]);
  }

#pragma unroll 1
  for (int t = 0; t < NKT; ++t) {
    int d = t & 1;
    asm volatile("s_waitcnt vmcnt(0)" ::: "memory");
    __builtin_amdgcn_s_barrier();
    __builtin_amdgcn_sched_barrier(0);

    const u16* Ab = &lA[d][0];
    const u16* Bb = &lB[d][0];
    // reads in consumption order: af[0], all B, af[1..7]
    bf16x8 af[8], af2[8], bf[4], bf2v[4];
    af[0]  = *(const bf16x8*)(Ab + adA[0][0]);
    af2[0] = *(const bf16x8*)(Ab + adA[0][1]);
#pragma unroll
    for (int j = 0; j < 4; ++j) {
      bf[j]   = *(const bf16x8*)(Bb + adB[j][0]);
      bf2v[j] = *(const bf16x8*)(Bb + adB[j][1]);
    }
#pragma unroll
    for (int f = 1; f < 8; ++f) {
      af[f]  = *(const bf16x8*)(Ab + adA[f][0]);
      af2[f] = *(const bf16x8*)(Ab + adA[f][1]);
    }

    if (t + 1 < NKT) {
#pragma unroll
      for (int c = 0; c < 4; ++c) {
        g2l16(aptr[c] + (t + 1) * 64, &lA[d ^ 1][(c * 512 + tid) * 8]);
        g2l16(bptr[c] + (t + 1) * 64, &lB[d ^ 1][(c * 512 + tid) * 8]);
      }
    }
    __builtin_amdgcn_sched_barrier(0);

    __builtin_amdgcn_s_setprio(1);
#pragma unroll
    for (int mi = 0; mi < 8; ++mi) {
#pragma unroll
      for (int ni = 0; ni < 4; ++ni)
        acc[mi][ni] = __builtin_amdgcn_mfma_f32_16x16x32_bf16(
            af[mi], bf[ni], acc[mi][ni], 0, 0, 0);
#pragma unroll
      for (int ni = 0; ni < 4; ++ni)
        acc[mi][ni] = __builtin_amdgcn_mfma_f32_16x16x32_bf16(
            af2[mi], bf2v[ni], acc[mi][ni], 0, 0, 0);
    }
    __builtin_amdgcn_s_setprio(0);
  }

  // epilogue: C/D layout col=lane&15, row=quad*4+reg
#pragma unroll
  for (int mi = 0; mi < 8; ++mi) {
    int rb = wr * 128 + mi * 16 + quad * 4;
#pragma unroll
    for (int r = 0; r < 4; ++r) {
      int grow = m0 + rb + r;
      if (grow < cnt) {
        if (FUSEOUT) {
          int tk = tope ? tok_list[e * T_TOK + grow] : 0;
          int pk = tope[tk];
          float2 gg = gate2[tk];
          float g = ((pk & 0xff) == e) ? gg.x : gg.y;
          float* orow = fout + (size_t)tk * H_DIM + nt * 256 + wc * 64 + l16;
#pragma unroll
          for (int ni = 0; ni < 4; ++ni)
            atomicAdd(orow + ni * 16, g * acc[mi][ni][r]);
        } else {
          size_t o = (size_t)(base + grow) * OUTN + nt * 256 + wc * 64 + l16;
#pragma unroll
          for (int ni = 0; ni < 4; ++ni) {
            float v = acc[mi][ni][r];
            if (GELU) v = fast_gelu(v);
            O[o + ni * 16] = f32_to_bf16(v);
          }
        }
      }
    }
  }
}

extern "C" void kernel_launch(void* const* d_in, const int* in_sizes, int n_in,
                              void* d_out, int out_size, void* d_ws, size_t ws_size,
                              hipStream_t stream) {
  const float* x  = (const float*)d_in[0];
  const float* rw = (const float*)d_in[1];
  const float* w1 = (const float*)d_in[2];
  const float* w2 = (const float*)d_in[3];
  float* out = (float*)d_out;

  // ws layout (bytes), total ~151 MB (y buffer eliminated)
  char* ws = (char*)d_ws;
  u16* xb       = (u16*)(ws);                        // 16,777,216
  u16* w1b      = (u16*)(ws + 16777216);             // 33,554,432
  u16* w2b      = (u16*)(ws + 50331648);             // 33,554,432
  u16* h        = (u16*)(ws + 83886080);             // 67,108,864
  int* tok_list = (int*)(ws + 150994944);            // 262,144
  int* tope     = (int*)(ws + 151257088);            // 32,768
  float2* gate2 = (float2*)(ws + 151289856);         // 65,536
  int* counts   = (int*)(ws + 151355392);            // 32

  // prep: router + zero counts + zero out (atomic target)
  prep_kernel<<<T_TOK / 4, 256, 0, stream>>>(x, rw, xb, tope, gate2, counts,
                                             out);
  // build: sort (32 blocks) + w1 cvt (2048 blocks)
  build_kernel<<<32 + 2048, 256, 0, stream>>>(tope, counts, tok_list, w1, w1b);
  // g1: gathered [cnt_e,1024](bf16) @ w1[e]^T -> gelu -> h [.,2048]
  //     mt>=16 (idle) blocks convert w2 f32->bf16 (exact coverage)
  moe_gemm<16, 8, H2, true, true, true, false>
      <<<NE * 32 * 8, 512, 0, stream>>>(xb, w1b, h, tok_list, counts, w2, w2b,
                                        nullptr, nullptr, nullptr);
  // g2: h [cnt_e,2048] @ w2[e]^T, gate fused, atomicAdd f32 -> out
  moe_gemm<32, 4, H_DIM, false, false, false, true>
      <<<NE * 32 * 4, 512, 0, stream>>>(h, w2b, nullptr, tok_list, counts,
                                        nullptr, nullptr, tope, gate2, out);
}